// Round 1
// baseline (123.815 us; speedup 1.0000x reference)
//
#include <hip/hip_runtime.h>

// SSDTableBatchedEmbeddingBags forward (SUM pooling).
// Shapes fixed by the reference: T=4 tables, B=8192, L=50, D=128, ROWS=250000.
// indices: int32 [T*B*L], offsets: int32 [T*B+1] (CSR, feature-major),
// weights: fp32 [T*ROWS, D], out: fp32 [B, T*D].

constexpr int T    = 4;
constexpr int B    = 8192;
constexpr int D    = 128;
constexpr int ROWS = 250000;
constexpr int BAGS = T * B;                 // 32768
constexpr int WAVES_PER_BLOCK = 4;          // 256 threads / 64

__global__ __launch_bounds__(256) void emb_bag_sum_kernel(
    const int*   __restrict__ indices,
    const int*   __restrict__ offsets,
    const float* __restrict__ weights,
    float*       __restrict__ out)
{
    const int lane = threadIdx.x & 63;
    const int wid  = threadIdx.x >> 6;
    const int bag  = blockIdx.x * WAVES_PER_BLOCK + wid;
    if (bag >= BAGS) return;

    const int t    = bag >> 13;             // bag / B  (B = 8192)
    const int b    = bag & (B - 1);
    const int base = t * ROWS;              // hash_size_cumsum linearization

    const int start = offsets[bag];
    const int end   = offsets[bag + 1];

    const int hi = lane >> 5;               // which row of the pair (0/1)
    const int dq = lane & 31;               // float4 slot within row (D/4=32)

    const float4* __restrict__ Wv = (const float4*)weights;

    float4 acc = make_float4(0.f, 0.f, 0.f, 0.f);

    int j = start;
    // main loop: 4 rows per iteration (2 pairs in flight for ILP)
    for (; j + 4 <= end; j += 4) {
        const int i0 = indices[j + hi];
        const int i1 = indices[j + 2 + hi];
        const float4 v0 = Wv[(long)(i0 + base) * (D / 4) + dq];
        const float4 v1 = Wv[(long)(i1 + base) * (D / 4) + dq];
        acc.x += v0.x; acc.y += v0.y; acc.z += v0.z; acc.w += v0.w;
        acc.x += v1.x; acc.y += v1.y; acc.z += v1.z; acc.w += v1.w;
    }
    // pair tail
    for (; j + 2 <= end; j += 2) {
        const int i0 = indices[j + hi];
        const float4 v0 = Wv[(long)(i0 + base) * (D / 4) + dq];
        acc.x += v0.x; acc.y += v0.y; acc.z += v0.z; acc.w += v0.w;
    }
    // odd single row: low half-wave handles it
    if (j < end && hi == 0) {
        const int i0 = indices[j];
        const float4 v0 = Wv[(long)(i0 + base) * (D / 4) + dq];
        acc.x += v0.x; acc.y += v0.y; acc.z += v0.z; acc.w += v0.w;
    }

    // combine the two half-wave partial sums (row-pair split)
    acc.x += __shfl_xor(acc.x, 32);
    acc.y += __shfl_xor(acc.y, 32);
    acc.z += __shfl_xor(acc.z, 32);
    acc.w += __shfl_xor(acc.w, 32);

    if (hi == 0) {
        // out[b, t*D + dq*4 .. +3]; row stride T*D = 512 floats = 128 float4
        float4* Ov = (float4*)out;
        Ov[(long)b * (T * D / 4) + t * (D / 4) + dq] = acc;
    }
}

extern "C" void kernel_launch(void* const* d_in, const int* in_sizes, int n_in,
                              void* d_out, int out_size, void* d_ws, size_t ws_size,
                              hipStream_t stream) {
    const int*   indices = (const int*)d_in[0];
    const int*   offsets = (const int*)d_in[1];
    const float* weights = (const float*)d_in[2];
    float*       out     = (float*)d_out;

    const int grid = BAGS / WAVES_PER_BLOCK;   // 8192 blocks x 256 threads
    emb_bag_sum_kernel<<<grid, 256, 0, stream>>>(indices, offsets, weights, out);
}

// Round 2
// 123.775 us; speedup vs baseline: 1.0003x; 1.0003x over previous
//
#include <hip/hip_runtime.h>

// SSDTableBatchedEmbeddingBags forward (SUM pooling).
// T=4 tables, B=8192, L=50, D=128, ROWS=250000.
// indices: int32 [T*B*L], offsets: int32 [T*B+1] (CSR, feature-major),
// weights: fp32 [T*ROWS, D], out: fp32 [B, T*D].
//
// One wave per bag. Lanes 0-31 take even rows, 32-63 odd rows; each lane holds
// one float4 (16 B) slice -> one global_load_dwordx4 covers 2 rows (1 KB/wave).
// All 50 bag indices are preloaded with a single coalesced load and sourced
// via __shfl, so row-gather addresses never wait on an index memory load.
// 8 rows unrolled -> 4 independent gathers in flight per wave.

constexpr int T    = 4;
constexpr int B    = 8192;
constexpr int D    = 128;
constexpr int ROWS = 250000;
constexpr int BAGS = T * B;                 // 32768
constexpr int WAVES_PER_BLOCK = 4;          // 256 threads / 64

__device__ __forceinline__ void acc4(float4& a, const float4& v) {
    a.x += v.x; a.y += v.y; a.z += v.z; a.w += v.w;
}

__global__ __launch_bounds__(256) void emb_bag_sum_kernel(
    const int*   __restrict__ indices,
    const int*   __restrict__ offsets,
    const float* __restrict__ weights,
    float*       __restrict__ out)
{
    const int lane = threadIdx.x & 63;
    const int wid  = threadIdx.x >> 6;
    const int bag  = blockIdx.x * WAVES_PER_BLOCK + wid;   // grid is exact

    const int t    = bag >> 13;             // bag / B  (B = 8192)
    const int b    = bag & (B - 1);
    const int base = t * ROWS;              // hash_size_cumsum linearization

    const int start = offsets[bag];
    const int end   = offsets[bag + 1];
    const int count = end - start;

    const int hi = lane >> 5;               // which row of the pair (0/1)
    const int dq = lane & 31;               // float4 slot within row (D/4=32)

    const float4* __restrict__ Wv = (const float4*)weights;

    float4 accA = make_float4(0.f, 0.f, 0.f, 0.f);
    float4 accB = make_float4(0.f, 0.f, 0.f, 0.f);

    if (count <= 64) {
        // fast path: whole bag's indices live in one register across the wave
        const int myidx = (lane < count) ? indices[start + lane] : 0;

        int j = 0;
        for (; j + 8 <= count; j += 8) {
            const int i0 = __shfl(myidx, j + 0 + hi);
            const int i1 = __shfl(myidx, j + 2 + hi);
            const int i2 = __shfl(myidx, j + 4 + hi);
            const int i3 = __shfl(myidx, j + 6 + hi);
            const float4 v0 = Wv[(long)(i0 + base) * (D / 4) + dq];
            const float4 v1 = Wv[(long)(i1 + base) * (D / 4) + dq];
            const float4 v2 = Wv[(long)(i2 + base) * (D / 4) + dq];
            const float4 v3 = Wv[(long)(i3 + base) * (D / 4) + dq];
            acc4(accA, v0); acc4(accB, v1); acc4(accA, v2); acc4(accB, v3);
        }
        for (; j + 2 <= count; j += 2) {
            const int i0 = __shfl(myidx, j + hi);
            const float4 v0 = Wv[(long)(i0 + base) * (D / 4) + dq];
            acc4(accA, v0);
        }
        if (j < count && hi == 0) {
            const int i0 = __shfl(myidx, j);
            const float4 v0 = Wv[(long)(i0 + base) * (D / 4) + dq];
            acc4(accA, v0);
        }
    } else {
        // generic fallback (not taken for L=50)
        int j = start;
        for (; j + 4 <= end; j += 4) {
            const int i0 = indices[j + hi];
            const int i1 = indices[j + 2 + hi];
            const float4 v0 = Wv[(long)(i0 + base) * (D / 4) + dq];
            const float4 v1 = Wv[(long)(i1 + base) * (D / 4) + dq];
            acc4(accA, v0); acc4(accB, v1);
        }
        for (; j + 2 <= end; j += 2) {
            const int i0 = indices[j + hi];
            const float4 v0 = Wv[(long)(i0 + base) * (D / 4) + dq];
            acc4(accA, v0);
        }
        if (j < end && hi == 0) {
            const int i0 = indices[j];
            const float4 v0 = Wv[(long)(i0 + base) * (D / 4) + dq];
            acc4(accA, v0);
        }
    }

    acc4(accA, accB);

    // combine the two half-wave partial sums (row-pair split)
    accA.x += __shfl_xor(accA.x, 32);
    accA.y += __shfl_xor(accA.y, 32);
    accA.z += __shfl_xor(accA.z, 32);
    accA.w += __shfl_xor(accA.w, 32);

    if (hi == 0) {
        // out[b, t*D + dq*4 .. +3]; row stride T*D = 512 floats = 128 float4
        float4* Ov = (float4*)out;
        Ov[(long)b * (T * D / 4) + t * (D / 4) + dq] = accA;
    }
}

extern "C" void kernel_launch(void* const* d_in, const int* in_sizes, int n_in,
                              void* d_out, int out_size, void* d_ws, size_t ws_size,
                              hipStream_t stream) {
    const int*   indices = (const int*)d_in[0];
    const int*   offsets = (const int*)d_in[1];
    const float* weights = (const float*)d_in[2];
    float*       out     = (float*)d_out;

    const int grid = BAGS / WAVES_PER_BLOCK;   // 8192 blocks x 256 threads
    emb_bag_sum_kernel<<<grid, 256, 0, stream>>>(indices, offsets, weights, out);
}